// Round 1
// baseline (223.266 us; speedup 1.0000x reference)
//
#include <hip/hip_runtime.h>

typedef __attribute__((ext_vector_type(8))) _Float16 half8;
typedef __attribute__((ext_vector_type(4))) float f32x4;

constexpr int Bc = 2, Sc = 2048, Dc = 1024, Hc = 16, HDc = 64;

// ---------------------------------------------------------------------------
// prep_wo: WoT[n][k'] = (f16) Wo[orig(k')][n], where k' = h*64+e, orig = e*16+h.
// Folds the head-interleave permutation of the attention output into Wo and
// transposes so GEMM B-tiles stage coalesced.
__global__ __launch_bounds__(256) void prep_wo(const float* __restrict__ Wo,
                                               _Float16* __restrict__ WoT) {
  __shared__ float T[64][68];
  const int hh = blockIdx.x;       // head index == k'-tile of 64
  const int n0 = blockIdx.y * 64;  // n tile
  const int tid = threadIdx.x;
#pragma unroll
  for (int i = 0; i < 4; ++i) {
    int g = tid + i * 256;
    int e = g >> 4, c4 = (g & 15) * 4;
    const float4 v = *(const float4*)(Wo + (size_t)(e * 16 + hh) * Dc + n0 + c4);
    *(float4*)&T[e][c4] = v;
  }
  __syncthreads();
#pragma unroll
  for (int i = 0; i < 4; ++i) {
    int g = tid + i * 256;
    int c = g >> 4, e4 = (g & 15) * 4;
    union { _Float16 h[4]; unsigned long long u; } pk;
    pk.h[0] = (_Float16)T[e4 + 0][c];
    pk.h[1] = (_Float16)T[e4 + 1][c];
    pk.h[2] = (_Float16)T[e4 + 2][c];
    pk.h[3] = (_Float16)T[e4 + 3][c];
    *(unsigned long long*)(WoT + (size_t)(n0 + c) * Dc + hh * 64 + e4) = pk.u;
  }
}

// ---------------------------------------------------------------------------
// qkv_proj: per (b,h,64-row tile): Q (pre-scaled), K as [BH,S,64] f16,
// V transposed -> Vt [BH,64,S] f16 (so PV B-frags read contiguous in t).
__global__ __launch_bounds__(256) void qkv_proj(
    const float* __restrict__ x, const float* __restrict__ Wq,
    const float* __restrict__ Wk, const float* __restrict__ Wv,
    _Float16* __restrict__ Qb, _Float16* __restrict__ Kb,
    _Float16* __restrict__ Vtb) {
  const int blk = blockIdx.x;
  const int st = blk & 31;           // S/64 = 32 tiles
  const int h  = (blk >> 5) & 15;
  const int b  = blk >> 9;
  const int s0 = st * 64;
  __shared__ __align__(16) float xs[64][64];
  __shared__ __align__(16) float wq[64][64];
  __shared__ __align__(16) float wk[64][64];
  __shared__ __align__(16) float wv[64][64];
  const int tid = threadIdx.x;
  const float* xbase = x + ((size_t)(b * Sc + s0)) * Dc + h * HDc;
  const float* wqp = Wq + h * HDc * HDc;
  const float* wkp = Wk + h * HDc * HDc;
  const float* wvp = Wv + h * HDc * HDc;
#pragma unroll
  for (int i = 0; i < 4; ++i) {
    int f = tid + i * 256;
    int r = f >> 4, c4 = (f & 15) * 4;
    *(float4*)&xs[r][c4] = *(const float4*)(xbase + (size_t)r * Dc + c4);
    *(float4*)&wq[r][c4] = *(const float4*)(wqp + r * 64 + c4);
    *(float4*)&wk[r][c4] = *(const float4*)(wkp + r * 64 + c4);
    *(float4*)&wv[r][c4] = *(const float4*)(wvp + r * 64 + c4);
  }
  __syncthreads();
  const int e = tid & 63, sg = tid >> 6;
  float aq[16], ak[16], av[16];
#pragma unroll
  for (int i = 0; i < 16; ++i) { aq[i] = 0.f; ak[i] = 0.f; av[i] = 0.f; }
  for (int d = 0; d < 64; ++d) {
    float wqv = wq[d][e], wkv = wk[d][e], wvv = wv[d][e];
#pragma unroll
    for (int i = 0; i < 16; ++i) {
      float xv = xs[sg * 16 + i][d];
      aq[i] = fmaf(xv, wqv, aq[i]);
      ak[i] = fmaf(xv, wkv, ak[i]);
      av[i] = fmaf(xv, wvv, av[i]);
    }
  }
  const size_t bh = (size_t)(b * Hc + h);
  const int sb = s0 + sg * 16;
#pragma unroll
  for (int i = 0; i < 16; ++i) {
    size_t qoff = (bh * Sc + sb + i) * HDc + e;
    Qb[qoff] = (_Float16)(aq[i] * 0.125f);   // fold 1/sqrt(64)
    Kb[qoff] = (_Float16)ak[i];
    Vtb[(bh * HDc + e) * Sc + sb + i] = (_Float16)av[i];
  }
}

// ---------------------------------------------------------------------------
// flash_attn: block = (b,h,64-row q-tile), 4 waves x 16 rows. KV tiles of 64.
// Online softmax in C-frag registers; P routed via per-wave LDS to PV A-frags.
__global__ __launch_bounds__(256) void flash_attn(
    const _Float16* __restrict__ Qb, const _Float16* __restrict__ Kb,
    const _Float16* __restrict__ Vtb, _Float16* __restrict__ attC) {
  const int blk = blockIdx.x;
  const int qb = blk & 31;
  const int h  = (blk >> 5) & 15;
  const int b  = blk >> 9;
  const int s0 = qb * 64;
  const size_t bh = (size_t)(b * Hc + h);
  __shared__ __align__(16) _Float16 Klds[64][72];
  __shared__ __align__(16) _Float16 Vlds[64][72];
  __shared__ __align__(16) _Float16 Plds[4][16][72];
  const int tid = threadIdx.x;
  const int l = tid & 63, w = tid >> 6;
  const int lr = l & 15, lg = l >> 4;

  // Q fragments for this wave's 16 rows (reused across all kv tiles)
  const _Float16* qptr = Qb + (bh * Sc + s0 + w * 16 + lr) * HDc + lg * 8;
  half8 aqf[2];
  aqf[0] = *(const half8*)(qptr);
  aqf[1] = *(const half8*)(qptr + 32);

  f32x4 acc[4] = {};
  float m_run[4], l_run[4];
#pragma unroll
  for (int r = 0; r < 4; ++r) { m_run[r] = -1e30f; l_run[r] = 0.f; }

  for (int kt = 0; kt <= qb; ++kt) {
    const int t0 = kt * 64;
#pragma unroll
    for (int i = 0; i < 4; ++i) {
      int q = tid + i * 256;
      int r = q >> 4, c4 = (q & 15) * 4;
      *(unsigned long long*)&Klds[r][c4] =
          *(const unsigned long long*)(Kb + (bh * Sc + t0 + r) * HDc + c4);
      *(unsigned long long*)&Vlds[r][c4] =
          *(const unsigned long long*)(Vtb + (bh * HDc + r) * Sc + t0 + c4);
    }
    __syncthreads();

    // scores: 16 rows x 64 keys (4 col-frags)
    f32x4 sc[4];
#pragma unroll
    for (int tc = 0; tc < 4; ++tc) {
      f32x4 s4 = {};
#pragma unroll
      for (int kk = 0; kk < 2; ++kk) {
        half8 bk = *(const half8*)&Klds[tc * 16 + lr][kk * 32 + lg * 8];
        s4 = __builtin_amdgcn_mfma_f32_16x16x32_f16(aqf[kk], bk, s4, 0, 0, 0);
      }
      sc[tc] = s4;
    }
    if (kt == qb) {  // diagonal tile: mask t_local > s_local
#pragma unroll
      for (int tc = 0; tc < 4; ++tc) {
        int tl = tc * 16 + lr;
#pragma unroll
        for (int r = 0; r < 4; ++r) {
          if (tl > w * 16 + lg * 4 + r) sc[tc][r] = -1e30f;
        }
      }
    }
    // online softmax (rows: lg*4+r; cols spread over 16 lanes x 4 frags)
    float mloc[4], mnew[4], corr[4], lsum[4];
#pragma unroll
    for (int r = 0; r < 4; ++r)
      mloc[r] = fmaxf(fmaxf(sc[0][r], sc[1][r]), fmaxf(sc[2][r], sc[3][r]));
#pragma unroll
    for (int off = 1; off < 16; off <<= 1)
#pragma unroll
      for (int r = 0; r < 4; ++r)
        mloc[r] = fmaxf(mloc[r], __shfl_xor(mloc[r], off));
#pragma unroll
    for (int r = 0; r < 4; ++r) {
      mnew[r] = fmaxf(m_run[r], mloc[r]);
      corr[r] = expf(m_run[r] - mnew[r]);
    }
#pragma unroll
    for (int tc = 0; tc < 4; ++tc)
#pragma unroll
      for (int r = 0; r < 4; ++r)
        sc[tc][r] = expf(sc[tc][r] - mnew[r]);
#pragma unroll
    for (int r = 0; r < 4; ++r)
      lsum[r] = sc[0][r] + sc[1][r] + sc[2][r] + sc[3][r];
#pragma unroll
    for (int off = 1; off < 16; off <<= 1)
#pragma unroll
      for (int r = 0; r < 4; ++r)
        lsum[r] += __shfl_xor(lsum[r], off);
#pragma unroll
    for (int r = 0; r < 4; ++r) {
      l_run[r] = l_run[r] * corr[r] + lsum[r];
      m_run[r] = mnew[r];
    }
#pragma unroll
    for (int ec = 0; ec < 4; ++ec)
#pragma unroll
      for (int r = 0; r < 4; ++r)
        acc[ec][r] *= corr[r];

    // P -> LDS (bf16-free: f16), then read back as PV A-frags
#pragma unroll
    for (int tc = 0; tc < 4; ++tc)
#pragma unroll
      for (int r = 0; r < 4; ++r)
        Plds[w][lg * 4 + r][tc * 16 + lr] = (_Float16)sc[tc][r];

    half8 pa[2];
    pa[0] = *(const half8*)&Plds[w][lr][lg * 8];
    pa[1] = *(const half8*)&Plds[w][lr][32 + lg * 8];
#pragma unroll
    for (int ec = 0; ec < 4; ++ec) {
#pragma unroll
      for (int k2 = 0; k2 < 2; ++k2) {
        half8 bv = *(const half8*)&Vlds[ec * 16 + lr][k2 * 32 + lg * 8];
        acc[ec] = __builtin_amdgcn_mfma_f32_16x16x32_f16(pa[k2], bv, acc[ec], 0, 0, 0);
      }
    }
    __syncthreads();
  }

  float inv[4];
#pragma unroll
  for (int r = 0; r < 4; ++r) inv[r] = 1.f / l_run[r];
#pragma unroll
  for (int ec = 0; ec < 4; ++ec)
#pragma unroll
    for (int r = 0; r < 4; ++r) {
      size_t row = (size_t)b * Sc + s0 + w * 16 + lg * 4 + r;
      attC[row * Dc + h * HDc + ec * 16 + lr] = (_Float16)(acc[ec][r] * inv[r]);
    }
}

// ---------------------------------------------------------------------------
// out_proj: C[4096][1024] = attC @ WoP + bo. 128x128 tile, BK=32, 4 waves.
__global__ __launch_bounds__(256) void out_proj(
    const _Float16* __restrict__ attC, const _Float16* __restrict__ WoT,
    const float* __restrict__ bo, float* __restrict__ out) {
  const int m0 = blockIdx.x * 128, n0 = blockIdx.y * 128;
  __shared__ __align__(16) _Float16 Alds[128][32];
  __shared__ __align__(16) _Float16 Blds[128][32];
  const int tid = threadIdx.x;
  const int l = tid & 63, w = tid >> 6;
  const int wm = w >> 1, wn = w & 1;
  const int lr = l & 15, lg = l >> 4;
  f32x4 acc[4][4] = {};
  for (int kt = 0; kt < 32; ++kt) {
    const int k0 = kt * 32;
#pragma unroll
    for (int i = 0; i < 2; ++i) {
      int g = tid + i * 256;
      int r = g >> 2, c8 = (g & 3) * 8;
      *(half8*)&Alds[r][c8] = *(const half8*)(attC + (size_t)(m0 + r) * Dc + k0 + c8);
      *(half8*)&Blds[r][c8] = *(const half8*)(WoT + (size_t)(n0 + r) * Dc + k0 + c8);
    }
    __syncthreads();
    half8 af[4], bf[4];
#pragma unroll
    for (int i2 = 0; i2 < 4; ++i2) {
      af[i2] = *(const half8*)&Alds[wm * 64 + i2 * 16 + lr][lg * 8];
      bf[i2] = *(const half8*)&Blds[wn * 64 + i2 * 16 + lr][lg * 8];
    }
#pragma unroll
    for (int am = 0; am < 4; ++am)
#pragma unroll
      for (int bn = 0; bn < 4; ++bn)
        acc[am][bn] = __builtin_amdgcn_mfma_f32_16x16x32_f16(af[am], bf[bn], acc[am][bn], 0, 0, 0);
    __syncthreads();
  }
#pragma unroll
  for (int am = 0; am < 4; ++am)
#pragma unroll
    for (int bn = 0; bn < 4; ++bn) {
      int n = n0 + wn * 64 + bn * 16 + lr;
      float bias = bo[n];
#pragma unroll
      for (int r = 0; r < 4; ++r) {
        int m = m0 + wm * 64 + am * 16 + lg * 4 + r;
        out[(size_t)m * Dc + n] = acc[am][bn][r] + bias;
      }
    }
}

// ---------------------------------------------------------------------------
extern "C" void kernel_launch(void* const* d_in, const int* in_sizes, int n_in,
                              void* d_out, int out_size, void* d_ws, size_t ws_size,
                              hipStream_t stream) {
  const float* x  = (const float*)d_in[0];
  const float* Wq = (const float*)d_in[1];
  const float* Wk = (const float*)d_in[2];
  const float* Wv = (const float*)d_in[3];
  const float* Wo = (const float*)d_in[4];
  const float* bo = (const float*)d_in[5];
  float* out = (float*)d_out;
  char* ws = (char*)d_ws;
  _Float16* Qb   = (_Float16*)(ws);                        // 8 MiB
  _Float16* Kb   = (_Float16*)(ws + (size_t)(8  << 20));   // 8 MiB
  _Float16* Vtb  = (_Float16*)(ws + (size_t)(16 << 20));   // 8 MiB
  _Float16* attC = (_Float16*)(ws + (size_t)(24 << 20));   // 8 MiB
  _Float16* WoT  = (_Float16*)(ws + (size_t)(32 << 20));   // 2 MiB

  prep_wo<<<dim3(16, 16), dim3(256), 0, stream>>>(Wo, WoT);
  qkv_proj<<<dim3(Bc * Hc * (Sc / 64)), dim3(256), 0, stream>>>(x, Wq, Wk, Wv, Qb, Kb, Vtb);
  flash_attn<<<dim3(Bc * Hc * (Sc / 64)), dim3(256), 0, stream>>>(Qb, Kb, Vtb, attC);
  out_proj<<<dim3(32, 8), dim3(256), 0, stream>>>(attC, WoT, bo, out);
}

// Round 4
// 119.128 us; speedup vs baseline: 1.8742x; 1.8742x over previous
//
#include <hip/hip_runtime.h>

typedef __attribute__((ext_vector_type(8))) _Float16 half8;
typedef __attribute__((ext_vector_type(2))) __fp16 fp16x2;
typedef __attribute__((ext_vector_type(4))) float f32x4;
typedef __attribute__((ext_vector_type(16))) float f32x16;

constexpr int Bc = 2, Sc = 2048, Dc = 1024, Hc = 16, HDc = 64;

// LDS swizzle for [rows][64] f16 tiles: XOR column-halfs with (row&7)*8.
// Breaks the 32-way bank conflict of 128B-pitch column-slice b128 reads -> 4-way.
__device__ __forceinline__ int swz(int row, int colh) {
  return row * 64 + (colh ^ ((row & 7) * 8));
}

// ---------------------------------------------------------------------------
// prep_w: WT[m][h][e][d] = (f16) W_m[h][d][e]  (transpose per head, cast f16).
// Wq additionally scaled by 0.125*log2(e) (folds softmax scale + exp2 domain).
__global__ __launch_bounds__(256) void prep_w(const float* __restrict__ Wq,
                                              const float* __restrict__ Wk,
                                              const float* __restrict__ Wv,
                                              _Float16* __restrict__ WT) {
  const int m = blockIdx.x >> 4;
  const int h = blockIdx.x & 15;
  const float* src = (m == 0 ? Wq : (m == 1 ? Wk : Wv)) + (size_t)h * 4096;
  const float scale = (m == 0) ? 0.125f * 1.44269504088896f : 1.0f;
  __shared__ float T[64][65];
  const int tid = threadIdx.x;
#pragma unroll
  for (int i = 0; i < 4; ++i) {
    int r = (tid >> 4) + 16 * i, c4 = (tid & 15) * 4;
    *(float4*)&T[r][c4] = *(const float4*)(src + r * 64 + c4);
  }
  __syncthreads();
  _Float16* dst = WT + ((size_t)m * 16 + h) * 4096;
#pragma unroll
  for (int i = 0; i < 4; ++i) {
    int e = (tid >> 4) + 16 * i, d4 = (tid & 15) * 4;
    union { _Float16 hh[4]; unsigned long long u; } pk;
#pragma unroll
    for (int j = 0; j < 4; ++j) pk.hh[j] = (_Float16)(T[d4 + j][e] * scale);
    *(unsigned long long*)(dst + (size_t)e * 64 + d4) = pk.u;
  }
}

// ---------------------------------------------------------------------------
// prep_wo: WoT[n][k'] = (f16) Wo[orig(k')][n], k' = h*64+e, orig = e*16+h.
__global__ __launch_bounds__(256) void prep_wo(const float* __restrict__ Wo,
                                               _Float16* __restrict__ WoT) {
  __shared__ float T[64][68];
  const int hh = blockIdx.x;
  const int n0 = blockIdx.y * 64;
  const int tid = threadIdx.x;
#pragma unroll
  for (int i = 0; i < 4; ++i) {
    int g = tid + i * 256;
    int e = g >> 4, c4 = (g & 15) * 4;
    *(float4*)&T[e][c4] = *(const float4*)(Wo + (size_t)(e * 16 + hh) * Dc + n0 + c4);
  }
  __syncthreads();
#pragma unroll
  for (int i = 0; i < 4; ++i) {
    int g = tid + i * 256;
    int c = g >> 4, e4 = (g & 15) * 4;
    union { _Float16 h[4]; unsigned long long u; } pk;
    pk.h[0] = (_Float16)T[e4 + 0][c];
    pk.h[1] = (_Float16)T[e4 + 1][c];
    pk.h[2] = (_Float16)T[e4 + 2][c];
    pk.h[3] = (_Float16)T[e4 + 3][c];
    *(unsigned long long*)(WoT + (size_t)(n0 + c) * Dc + hh * 64 + e4) = pk.u;
  }
}

// ---------------------------------------------------------------------------
// qkv_proj (MFMA): block = (b, 128-row s-tile, h). 4 waves x 32 s-rows.
// Q/K -> [bh][s][64]; V -> transposed [bh][64][S] directly via mfma(Wv^T, x^T).
__global__ __launch_bounds__(256) void qkv_proj(
    const float* __restrict__ x, const _Float16* __restrict__ WT,
    _Float16* __restrict__ Qb, _Float16* __restrict__ Kb,
    _Float16* __restrict__ Vtb) {
  const int h = blockIdx.x & 15;
  const int st = (blockIdx.x >> 4) & 15;
  const int b = blockIdx.x >> 8;
  const int s0 = st * 128;
  __shared__ __align__(16) _Float16 xs[128 * 64];
  const int tid = threadIdx.x;
#pragma unroll
  for (int i = 0; i < 4; ++i) {
    int r = (tid >> 3) + 32 * i;
    int c8 = (tid & 7) * 8;
    const float* xp = x + ((size_t)(b * Sc + s0 + r)) * Dc + h * 64 + c8;
    float4 u0 = *(const float4*)xp;
    float4 u1 = *(const float4*)(xp + 4);
    union { fp16x2 h2[4]; half8 h8; } pk;
    pk.h2[0] = __builtin_amdgcn_cvt_pkrtz(u0.x, u0.y);
    pk.h2[1] = __builtin_amdgcn_cvt_pkrtz(u0.z, u0.w);
    pk.h2[2] = __builtin_amdgcn_cvt_pkrtz(u1.x, u1.y);
    pk.h2[3] = __builtin_amdgcn_cvt_pkrtz(u1.z, u1.w);
    *(half8*)&xs[swz(r, c8)] = pk.h8;
  }
  __syncthreads();
  const int l = tid & 63, w = tid >> 6;
  const int lq = l & 31, hi = l >> 5;
  half8 xa[4];
#pragma unroll
  for (int c = 0; c < 4; ++c)
    xa[c] = *(const half8*)&xs[swz(32 * w + lq, c * 16 + hi * 8)];

  const _Float16* WTq = WT + (size_t)h * 4096;
  const _Float16* WTk = WT + (size_t)(16 + h) * 4096;
  const _Float16* WTv = WT + (size_t)(32 + h) * 4096;
  f32x16 Qa[2] = {}, Ka[2] = {}, Va[2] = {};
#pragma unroll
  for (int et = 0; et < 2; ++et) {
#pragma unroll
    for (int c = 0; c < 4; ++c) {
      const int off = (32 * et + lq) * 64 + c * 16 + hi * 8;
      half8 wqf = *(const half8*)(WTq + off);
      half8 wkf = *(const half8*)(WTk + off);
      half8 wvf = *(const half8*)(WTv + off);
      Qa[et] = __builtin_amdgcn_mfma_f32_32x32x16_f16(xa[c], wqf, Qa[et], 0, 0, 0);
      Ka[et] = __builtin_amdgcn_mfma_f32_32x32x16_f16(xa[c], wkf, Ka[et], 0, 0, 0);
      Va[et] = __builtin_amdgcn_mfma_f32_32x32x16_f16(wvf, xa[c], Va[et], 0, 0, 0);
    }
  }
  const size_t bh = (size_t)(b * Hc + h);
#pragma unroll
  for (int et = 0; et < 2; ++et)
#pragma unroll
    for (int r = 0; r < 16; ++r) {
      int rr = (r & 3) + 8 * (r >> 2) + 4 * hi;
      size_t so = (bh * Sc + s0 + 32 * w + rr) * 64 + 32 * et + lq;
      Qb[so] = (_Float16)Qa[et][r];
      Kb[so] = (_Float16)Ka[et][r];
      Vtb[(bh * 64 + 32 * et + rr) * Sc + s0 + 32 * w + lq] = (_Float16)Va[et][r];
    }
}

// ---------------------------------------------------------------------------
// flash_attn v2.1: swapped QK^T (S^T = K·Q^T) AND swapped PV (O^T = V^T·P^T)
// so every accumulator element belongs to the lane's own q (col = lane&31) and
// the per-lane online-softmax state applies uniformly. K/V LDS XOR-swizzled.
__global__ __launch_bounds__(256) void flash_attn(
    const _Float16* __restrict__ Qb, const _Float16* __restrict__ Kb,
    const _Float16* __restrict__ Vtb, _Float16* __restrict__ attC) {
  const int bh = blockIdx.x & 31;
  const int qt = 15 - (blockIdx.x >> 5);   // longest tiles first (LPT)
  const int qb0 = qt * 128;
  const int NT = 2 * qt + 2;
  const int b = bh >> 4, h = bh & 15;
  __shared__ __align__(16) _Float16 Kl[64 * 64];
  __shared__ __align__(16) _Float16 Vl[64 * 64];
  const int tid = threadIdx.x;
  const int w = tid >> 6, l = tid & 63;
  const int lq = l & 31, hi = l >> 5;
  const int qg_min = qb0 + 32 * w;
  const int q_global = qg_min + lq;

  const _Float16* qp = Qb + ((size_t)bh * Sc + q_global) * 64 + hi * 8;
  half8 qf[4];
#pragma unroll
  for (int c = 0; c < 4; ++c) qf[c] = *(const half8*)(qp + c * 16);

  f32x16 OA = {}, OB = {};
  float m_run = -1e30f, l_run = 0.f;

  const int srow = tid >> 3;
  const int sc8 = (tid & 7) * 8;
  const _Float16* kgp = Kb + ((size_t)bh * Sc) * 64;
  const _Float16* vgp = Vtb + ((size_t)bh * 64) * Sc;

  for (int kt = 0; kt < NT; ++kt) {
    const int k0 = kt * 64;
#pragma unroll
    for (int p = 0; p < 2; ++p) {
      int r = srow + 32 * p;
      *(half8*)&Kl[swz(r, sc8)] = *(const half8*)(kgp + (size_t)(k0 + r) * 64 + sc8);
      *(half8*)&Vl[swz(r, sc8)] = *(const half8*)(vgp + (size_t)r * Sc + k0 + sc8);
    }
    __syncthreads();
    if (k0 <= qg_min + 31) {
      f32x16 SA = {}, SB = {};
      __builtin_amdgcn_s_setprio(1);
#pragma unroll
      for (int c = 0; c < 4; ++c) {
        half8 ka = *(const half8*)&Kl[swz(lq, c * 16 + hi * 8)];
        half8 kb = *(const half8*)&Kl[swz(32 + lq, c * 16 + hi * 8)];
        SA = __builtin_amdgcn_mfma_f32_32x32x16_f16(ka, qf[c], SA, 0, 0, 0);
        SB = __builtin_amdgcn_mfma_f32_32x32x16_f16(kb, qf[c], SB, 0, 0, 0);
      }
      __builtin_amdgcn_s_setprio(0);
      if (k0 + 63 > qg_min) {  // diagonal tile: causal mask per element
#pragma unroll
        for (int r = 0; r < 16; ++r) {
          int kk = k0 + (r & 3) + 8 * (r >> 2) + 4 * hi;
          if (kk > q_global) SA[r] = -1e30f;
          if (kk + 32 > q_global) SB[r] = -1e30f;
        }
      }
      float mx = -1e30f;
#pragma unroll
      for (int r = 0; r < 16; ++r) mx = fmaxf(mx, fmaxf(SA[r], SB[r]));
      mx = fmaxf(mx, __shfl_xor(mx, 32));
      float mnew = fmaxf(m_run, mx);
      float Pv[32];
      float ls = 0.f;
#pragma unroll
      for (int r = 0; r < 16; ++r) {
        float a = exp2f(SA[r] - mnew);
        float bq = exp2f(SB[r] - mnew);
        Pv[r] = a; Pv[16 + r] = bq;
        ls += a + bq;
      }
      ls += __shfl_xor(ls, 32);
      float corr = exp2f(m_run - mnew);
      m_run = mnew;
      l_run = l_run * corr + ls;
#pragma unroll
      for (int r = 0; r < 16; ++r) { OA[r] *= corr; OB[r] *= corr; }
      __builtin_amdgcn_s_setprio(1);
#pragma unroll
      for (int ch = 0; ch < 4; ++ch) {
        unsigned W0 = __builtin_bit_cast(unsigned, __builtin_amdgcn_cvt_pkrtz(Pv[ch * 8 + 0], Pv[ch * 8 + 1]));
        unsigned W1 = __builtin_bit_cast(unsigned, __builtin_amdgcn_cvt_pkrtz(Pv[ch * 8 + 2], Pv[ch * 8 + 3]));
        unsigned W2 = __builtin_bit_cast(unsigned, __builtin_amdgcn_cvt_pkrtz(Pv[ch * 8 + 4], Pv[ch * 8 + 5]));
        unsigned W3 = __builtin_bit_cast(unsigned, __builtin_amdgcn_cvt_pkrtz(Pv[ch * 8 + 6], Pv[ch * 8 + 7]));
        unsigned sw0 = (unsigned)__shfl_xor((int)(hi ? W0 : W2), 32);
        unsigned sw1 = (unsigned)__shfl_xor((int)(hi ? W1 : W3), 32);
        union { unsigned u[4]; half8 h; } pa;
        pa.u[0] = hi ? sw0 : W0;
        pa.u[1] = hi ? sw1 : W1;
        pa.u[2] = hi ? W2 : sw0;
        pa.u[3] = hi ? W3 : sw1;
        half8 bv0 = *(const half8*)&Vl[swz(lq, ch * 16 + hi * 8)];
        half8 bv1 = *(const half8*)&Vl[swz(32 + lq, ch * 16 + hi * 8)];
        // O^T = V^T · P^T : A = V^T-frag (rows e), B = P^T-frag (col = lane's q)
        OA = __builtin_amdgcn_mfma_f32_32x32x16_f16(bv0, pa.h, OA, 0, 0, 0);
        OB = __builtin_amdgcn_mfma_f32_32x32x16_f16(bv1, pa.h, OB, 0, 0, 0);
      }
      __builtin_amdgcn_s_setprio(0);
    }
    __syncthreads();
  }
  // OA[r] = O^T[e = (r&3)+8*(r>>2)+4*hi][q = q_global]; OB -> e+32.
  float inv = 1.f / l_run;
  _Float16* op = attC + ((size_t)b * Sc + q_global) * Dc + h * 64;
#pragma unroll
  for (int g = 0; g < 4; ++g) {
    union { _Float16 hh[4]; unsigned long long u; } pA, pB;
#pragma unroll
    for (int j = 0; j < 4; ++j) {
      pA.hh[j] = (_Float16)(OA[4 * g + j] * inv);
      pB.hh[j] = (_Float16)(OB[4 * g + j] * inv);
    }
    *(unsigned long long*)(op + 8 * g + 4 * hi) = pA.u;
    *(unsigned long long*)(op + 32 + 8 * g + 4 * hi) = pB.u;
  }
}

// ---------------------------------------------------------------------------
// out_proj: C[4096][1024] = attC @ WoT^T + bo. 128x128 tile, BK=32, 4 waves.
__global__ __launch_bounds__(256) void out_proj(
    const _Float16* __restrict__ attC, const _Float16* __restrict__ WoT,
    const float* __restrict__ bo, float* __restrict__ out) {
  const int m0 = blockIdx.x * 128, n0 = blockIdx.y * 128;
  __shared__ __align__(16) _Float16 Alds[128][32];
  __shared__ __align__(16) _Float16 Blds[128][32];
  const int tid = threadIdx.x;
  const int l = tid & 63, w = tid >> 6;
  const int wm = w >> 1, wn = w & 1;
  const int lr = l & 15, lg = l >> 4;
  f32x4 acc[4][4] = {};
  for (int kt = 0; kt < 32; ++kt) {
    const int k0 = kt * 32;
#pragma unroll
    for (int i = 0; i < 2; ++i) {
      int g = tid + i * 256;
      int r = g >> 2, c8 = (g & 3) * 8;
      *(half8*)&Alds[r][c8] = *(const half8*)(attC + (size_t)(m0 + r) * Dc + k0 + c8);
      *(half8*)&Blds[r][c8] = *(const half8*)(WoT + (size_t)(n0 + r) * Dc + k0 + c8);
    }
    __syncthreads();
    half8 af[4], bf[4];
#pragma unroll
    for (int i2 = 0; i2 < 4; ++i2) {
      af[i2] = *(const half8*)&Alds[wm * 64 + i2 * 16 + lr][lg * 8];
      bf[i2] = *(const half8*)&Blds[wn * 64 + i2 * 16 + lr][lg * 8];
    }
#pragma unroll
    for (int am = 0; am < 4; ++am)
#pragma unroll
      for (int bn = 0; bn < 4; ++bn)
        acc[am][bn] = __builtin_amdgcn_mfma_f32_16x16x32_f16(af[am], bf[bn], acc[am][bn], 0, 0, 0);
    __syncthreads();
  }
#pragma unroll
  for (int am = 0; am < 4; ++am)
#pragma unroll
    for (int bn = 0; bn < 4; ++bn) {
      int n = n0 + wn * 64 + bn * 16 + lr;
      float bias = bo[n];
#pragma unroll
      for (int r = 0; r < 4; ++r) {
        int m = m0 + wm * 64 + am * 16 + lg * 4 + r;
        out[(size_t)m * Dc + n] = acc[am][bn][r] + bias;
      }
    }
}

// ---------------------------------------------------------------------------
extern "C" void kernel_launch(void* const* d_in, const int* in_sizes, int n_in,
                              void* d_out, int out_size, void* d_ws, size_t ws_size,
                              hipStream_t stream) {
  const float* x  = (const float*)d_in[0];
  const float* Wq = (const float*)d_in[1];
  const float* Wk = (const float*)d_in[2];
  const float* Wv = (const float*)d_in[3];
  const float* Wo = (const float*)d_in[4];
  const float* bo = (const float*)d_in[5];
  float* out = (float*)d_out;
  char* ws = (char*)d_ws;
  _Float16* Qb   = (_Float16*)(ws);                        // [0,8M)
  _Float16* Kb   = (_Float16*)(ws + (size_t)(8  << 20));   // [8M,16M)
  _Float16* Vtb  = (_Float16*)(ws + (size_t)(16 << 20));   // [16M,24M)
  _Float16* WoT  = (_Float16*)(ws + (size_t)(24 << 20));   // [24M,26M)
  _Float16* WT   = (_Float16*)(ws + (size_t)(26 << 20));   // [26M,26.4M) dead after qkv
  _Float16* attC = (_Float16*)(ws + (size_t)(26 << 20));   // [26M,34M) written in flash

  prep_w<<<dim3(48), dim3(256), 0, stream>>>(Wq, Wk, Wv, WT);
  prep_wo<<<dim3(16, 16), dim3(256), 0, stream>>>(Wo, WoT);
  qkv_proj<<<dim3(512), dim3(256), 0, stream>>>(x, WT, Qb, Kb, Vtb);
  flash_attn<<<dim3(512), dim3(256), 0, stream>>>(Qb, Kb, Vtb, attC);
  out_proj<<<dim3(32, 8), dim3(256), 0, stream>>>(attC, WoT, bo, out);
}

// Round 5
// 100.396 us; speedup vs baseline: 2.2239x; 1.1866x over previous
//
#include <hip/hip_runtime.h>

typedef __attribute__((ext_vector_type(8))) _Float16 half8;
typedef __attribute__((ext_vector_type(2))) __fp16 fp16x2;
typedef __attribute__((ext_vector_type(4))) float f32x4;
typedef __attribute__((ext_vector_type(16))) float f32x16;

constexpr int Bc = 2, Sc = 2048, Dc = 1024, Hc = 16, HDc = 64;

// LDS swizzle for [rows][64] f16 tiles (qkv_proj x-tile only).
__device__ __forceinline__ int swz(int row, int colh) {
  return row * 64 + (colh ^ ((row & 7) * 8));
}

// ---------------------------------------------------------------------------
// prep_w: WT[m][h][e][d] = (f16) W_m[h][d][e]  (transpose per head, cast f16).
// Wq additionally scaled by 0.125*log2(e) (folds softmax scale + exp2 domain).
__global__ __launch_bounds__(256) void prep_w(const float* __restrict__ Wq,
                                              const float* __restrict__ Wk,
                                              const float* __restrict__ Wv,
                                              _Float16* __restrict__ WT) {
  const int m = blockIdx.x >> 4;
  const int h = blockIdx.x & 15;
  const float* src = (m == 0 ? Wq : (m == 1 ? Wk : Wv)) + (size_t)h * 4096;
  const float scale = (m == 0) ? 0.125f * 1.44269504088896f : 1.0f;
  __shared__ float T[64][65];
  const int tid = threadIdx.x;
#pragma unroll
  for (int i = 0; i < 4; ++i) {
    int r = (tid >> 4) + 16 * i, c4 = (tid & 15) * 4;
    *(float4*)&T[r][c4] = *(const float4*)(src + r * 64 + c4);
  }
  __syncthreads();
  _Float16* dst = WT + ((size_t)m * 16 + h) * 4096;
#pragma unroll
  for (int i = 0; i < 4; ++i) {
    int e = (tid >> 4) + 16 * i, d4 = (tid & 15) * 4;
    union { _Float16 hh[4]; unsigned long long u; } pk;
#pragma unroll
    for (int j = 0; j < 4; ++j) pk.hh[j] = (_Float16)(T[d4 + j][e] * scale);
    *(unsigned long long*)(dst + (size_t)e * 64 + d4) = pk.u;
  }
}

// ---------------------------------------------------------------------------
// prep_wo: WoT[n][k'] = (f16) Wo[orig(k')][n], k' = h*64+e, orig = e*16+h.
__global__ __launch_bounds__(256) void prep_wo(const float* __restrict__ Wo,
                                               _Float16* __restrict__ WoT) {
  __shared__ float T[64][68];
  const int hh = blockIdx.x;
  const int n0 = blockIdx.y * 64;
  const int tid = threadIdx.x;
#pragma unroll
  for (int i = 0; i < 4; ++i) {
    int g = tid + i * 256;
    int e = g >> 4, c4 = (g & 15) * 4;
    *(float4*)&T[e][c4] = *(const float4*)(Wo + (size_t)(e * 16 + hh) * Dc + n0 + c4);
  }
  __syncthreads();
#pragma unroll
  for (int i = 0; i < 4; ++i) {
    int g = tid + i * 256;
    int c = g >> 4, e4 = (g & 15) * 4;
    union { _Float16 h[4]; unsigned long long u; } pk;
    pk.h[0] = (_Float16)T[e4 + 0][c];
    pk.h[1] = (_Float16)T[e4 + 1][c];
    pk.h[2] = (_Float16)T[e4 + 2][c];
    pk.h[3] = (_Float16)T[e4 + 3][c];
    *(unsigned long long*)(WoT + (size_t)(n0 + c) * Dc + hh * 64 + e4) = pk.u;
  }
}

// ---------------------------------------------------------------------------
// qkv_proj (MFMA): block = (b, 128-row s-tile, h). 4 waves x 32 s-rows.
// Outputs in MFMA-FRAGMENT order (chunk = 512 halves = 64 lanes x 8):
//  Q'[(bh*64+qt)*4 + (e>>4)]  lane=((e>>3)&1)*32+(s&31), elem=e&7   (qt=s>>5)
//  K'[(bh*32+kt)*8 + ((s>>5)&1)*4 + (e>>4)] lane=((e>>3)&1)*32+(s&31), elem=e&7
//  V'[(bh*32+kt)*8 + (e>>5)*4 + ((s>>4)&3)] lane=((s>>3)&1)*32+(e&31), elem=s&7
__global__ __launch_bounds__(256) void qkv_proj(
    const float* __restrict__ x, const _Float16* __restrict__ WT,
    _Float16* __restrict__ Qp, _Float16* __restrict__ Kp,
    _Float16* __restrict__ Vp) {
  const int h = blockIdx.x & 15;
  const int st = (blockIdx.x >> 4) & 15;
  const int b = blockIdx.x >> 8;
  const int s0 = st * 128;
  __shared__ __align__(16) _Float16 xs[128 * 64];
  const int tid = threadIdx.x;
#pragma unroll
  for (int i = 0; i < 4; ++i) {
    int r = (tid >> 3) + 32 * i;
    int c8 = (tid & 7) * 8;
    const float* xp = x + ((size_t)(b * Sc + s0 + r)) * Dc + h * 64 + c8;
    float4 u0 = *(const float4*)xp;
    float4 u1 = *(const float4*)(xp + 4);
    union { fp16x2 h2[4]; half8 h8; } pk;
    pk.h2[0] = __builtin_amdgcn_cvt_pkrtz(u0.x, u0.y);
    pk.h2[1] = __builtin_amdgcn_cvt_pkrtz(u0.z, u0.w);
    pk.h2[2] = __builtin_amdgcn_cvt_pkrtz(u1.x, u1.y);
    pk.h2[3] = __builtin_amdgcn_cvt_pkrtz(u1.z, u1.w);
    *(half8*)&xs[swz(r, c8)] = pk.h8;
  }
  __syncthreads();
  const int l = tid & 63, w = tid >> 6;
  const int lq = l & 31, hi = l >> 5;
  half8 xa[4];
#pragma unroll
  for (int c = 0; c < 4; ++c)
    xa[c] = *(const half8*)&xs[swz(32 * w + lq, c * 16 + hi * 8)];

  const _Float16* WTq = WT + (size_t)h * 4096;
  const _Float16* WTk = WT + (size_t)(16 + h) * 4096;
  const _Float16* WTv = WT + (size_t)(32 + h) * 4096;
  f32x16 Qa[2] = {}, Ka[2] = {}, Va[2] = {};
#pragma unroll
  for (int et = 0; et < 2; ++et) {
#pragma unroll
    for (int c = 0; c < 4; ++c) {
      const int off = (32 * et + lq) * 64 + c * 16 + hi * 8;
      half8 wqf = *(const half8*)(WTq + off);
      half8 wkf = *(const half8*)(WTk + off);
      half8 wvf = *(const half8*)(WTv + off);
      Qa[et] = __builtin_amdgcn_mfma_f32_32x32x16_f16(xa[c], wqf, Qa[et], 0, 0, 0);
      Ka[et] = __builtin_amdgcn_mfma_f32_32x32x16_f16(xa[c], wkf, Ka[et], 0, 0, 0);
      Va[et] = __builtin_amdgcn_mfma_f32_32x32x16_f16(wvf, xa[c], Va[et], 0, 0, 0);
    }
  }
  const int bh = b * Hc + h;
  const size_t bhQ = (size_t)bh * 64;
  const size_t bhKV = (size_t)bh * 32;
#pragma unroll
  for (int et = 0; et < 2; ++et)
#pragma unroll
    for (int r = 0; r < 16; ++r) {
      const int rr = (r & 3) + 8 * (r >> 2) + 4 * hi;
      const int s = s0 + 32 * w + rr;
      const int e = 32 * et + lq;
      size_t qoff = (((bhQ + (s >> 5)) * 4 + (e >> 4)) << 9)
                  + ((((e >> 3) & 1) * 32 + (s & 31)) << 3) + (e & 7);
      Qp[qoff] = (_Float16)Qa[et][r];
      size_t koff = (((bhKV + (s >> 6)) * 8 + ((s >> 5) & 1) * 4 + (e >> 4)) << 9)
                  + ((((e >> 3) & 1) * 32 + (s & 31)) << 3) + (e & 7);
      Kp[koff] = (_Float16)Ka[et][r];
      const int ev = 32 * et + rr;
      const int sv = s0 + 32 * w + lq;
      size_t voff = (((bhKV + (sv >> 6)) * 8 + (ev >> 5) * 4 + ((sv >> 4) & 3)) << 9)
                  + ((((sv >> 3) & 1) * 32 + (ev & 31)) << 3) + (sv & 7);
      Vp[voff] = (_Float16)Va[et][r];
    }
}

// ---------------------------------------------------------------------------
// flash_attn v3: 1 wave/block, 32 q-rows, no LDS, no barriers. 2048 blocks,
// XCD-grouped (4 bh per XCD) + LPT (long q-tiles first). All operand loads
// are coalesced dwordx4 from pre-fragmented Q'/K'/V'. Swapped QK^T and PV
// keep softmax state per-lane; defer-max (THR=4) skips most rescales.
__global__ __launch_bounds__(64, 2) void flash_attn(
    const _Float16* __restrict__ Qp, const _Float16* __restrict__ Kp,
    const _Float16* __restrict__ Vp, _Float16* __restrict__ attC) {
  const int i = blockIdx.x;
  const int xcd = i & 7, j = i >> 3;
  const int bh = xcd * 4 + (j & 3);
  const int qt = 63 - (j >> 2);
  const int q0 = qt * 32;
  const int NT = qt / 2 + 1;
  const int b = bh >> 4, h = bh & 15;
  const int l = threadIdx.x, lq = l & 31, hi = l >> 5;
  const int q_global = q0 + lq;

  const _Float16* qb = Qp + (((size_t)(bh * 64 + qt) * 4) << 9) + (l << 3);
  half8 qf[4];
#pragma unroll
  for (int c = 0; c < 4; ++c) qf[c] = *(const half8*)(qb + (c << 9));

  f32x16 OA = {}, OB = {};
  float m_run = -1e30f, l_run = 0.f;

  for (int kt = 0; kt < NT; ++kt) {
    const int k0 = kt * 64;
    const bool doB = (k0 + 32) <= (q0 + 31);
    const size_t cb = ((size_t)(bh * 32 + kt) * 8) << 9;
    const _Float16* kb8 = Kp + cb + (l << 3);
    const _Float16* vb8 = Vp + cb + (l << 3);
    half8 ka[4], kb[4], va[4], vb[4];
#pragma unroll
    for (int c = 0; c < 4; ++c) {
      ka[c] = *(const half8*)(kb8 + (c << 9));
      va[c] = *(const half8*)(vb8 + (c << 9));
      vb[c] = *(const half8*)(vb8 + ((4 + c) << 9));
    }
    if (doB) {
#pragma unroll
      for (int c = 0; c < 4; ++c) kb[c] = *(const half8*)(kb8 + ((4 + c) << 9));
    }
    f32x16 SA = {}, SB = {};
    __builtin_amdgcn_s_setprio(1);
#pragma unroll
    for (int c = 0; c < 4; ++c)
      SA = __builtin_amdgcn_mfma_f32_32x32x16_f16(ka[c], qf[c], SA, 0, 0, 0);
    if (doB) {
#pragma unroll
      for (int c = 0; c < 4; ++c)
        SB = __builtin_amdgcn_mfma_f32_32x32x16_f16(kb[c], qf[c], SB, 0, 0, 0);
    }
    __builtin_amdgcn_s_setprio(0);
    if (k0 + 63 > q0) {  // diagonal tile: causal mask per element
#pragma unroll
      for (int r = 0; r < 16; ++r) {
        const int kk = k0 + (r & 3) + 8 * (r >> 2) + 4 * hi;
        if (kk > q_global) SA[r] = -1e30f;
        if (doB && kk + 32 > q_global) SB[r] = -1e30f;
      }
    }
    float mx = -1e30f;
#pragma unroll
    for (int r = 0; r < 16; ++r) mx = fmaxf(mx, SA[r]);
    if (doB) {
#pragma unroll
      for (int r = 0; r < 16; ++r) mx = fmaxf(mx, SB[r]);
    }
    mx = fmaxf(mx, __shfl_xor(mx, 32));
    if (!__all(mx <= m_run + 4.0f)) {  // defer-max: rescale only on growth
      const float mnew = fmaxf(m_run, mx);
      const float corr = __builtin_amdgcn_exp2f(m_run - mnew);
      l_run *= corr;
#pragma unroll
      for (int r = 0; r < 16; ++r) { OA[r] *= corr; OB[r] *= corr; }
      m_run = mnew;
    }
    float Pv[32];
    float ls = 0.f;
#pragma unroll
    for (int r = 0; r < 16; ++r) {
      Pv[r] = __builtin_amdgcn_exp2f(SA[r] - m_run);
      ls += Pv[r];
    }
    if (doB) {
#pragma unroll
      for (int r = 0; r < 16; ++r) {
        Pv[16 + r] = __builtin_amdgcn_exp2f(SB[r] - m_run);
        ls += Pv[16 + r];
      }
    }
    ls += __shfl_xor(ls, 32);
    l_run += ls;
    __builtin_amdgcn_s_setprio(1);
#pragma unroll
    for (int ch = 0; ch < 4; ++ch) {
      if (ch < (doB ? 4 : 2)) {
        unsigned W0 = __builtin_bit_cast(unsigned, __builtin_amdgcn_cvt_pkrtz(Pv[ch * 8 + 0], Pv[ch * 8 + 1]));
        unsigned W1 = __builtin_bit_cast(unsigned, __builtin_amdgcn_cvt_pkrtz(Pv[ch * 8 + 2], Pv[ch * 8 + 3]));
        unsigned W2 = __builtin_bit_cast(unsigned, __builtin_amdgcn_cvt_pkrtz(Pv[ch * 8 + 4], Pv[ch * 8 + 5]));
        unsigned W3 = __builtin_bit_cast(unsigned, __builtin_amdgcn_cvt_pkrtz(Pv[ch * 8 + 6], Pv[ch * 8 + 7]));
        unsigned sw0 = (unsigned)__shfl_xor((int)(hi ? W0 : W2), 32);
        unsigned sw1 = (unsigned)__shfl_xor((int)(hi ? W1 : W3), 32);
        union { unsigned u[4]; half8 h; } pa;
        pa.u[0] = hi ? sw0 : W0;
        pa.u[1] = hi ? sw1 : W1;
        pa.u[2] = hi ? W2 : sw0;
        pa.u[3] = hi ? W3 : sw1;
        OA = __builtin_amdgcn_mfma_f32_32x32x16_f16(va[ch], pa.h, OA, 0, 0, 0);
        OB = __builtin_amdgcn_mfma_f32_32x32x16_f16(vb[ch], pa.h, OB, 0, 0, 0);
      }
    }
    __builtin_amdgcn_s_setprio(0);
  }
  // OA[r] = O^T[e = (r&3)+8*(r>>2)+4*hi][q_global]; OB -> e+32.
  const float inv = 1.f / l_run;
  _Float16* op = attC + ((size_t)b * Sc + q_global) * Dc + h * 64;
#pragma unroll
  for (int g = 0; g < 4; ++g) {
    union { _Float16 hh[4]; unsigned long long u; } pA, pB;
#pragma unroll
    for (int jj = 0; jj < 4; ++jj) {
      pA.hh[jj] = (_Float16)(OA[4 * g + jj] * inv);
      pB.hh[jj] = (_Float16)(OB[4 * g + jj] * inv);
    }
    *(unsigned long long*)(op + 8 * g + 4 * hi) = pA.u;
    *(unsigned long long*)(op + 32 + 8 * g + 4 * hi) = pB.u;
  }
}

// ---------------------------------------------------------------------------
// out_proj: C[4096][1024] = attC @ WoT^T + bo. 128x128 tile, BK=32, 4 waves.
__global__ __launch_bounds__(256) void out_proj(
    const _Float16* __restrict__ attC, const _Float16* __restrict__ WoT,
    const float* __restrict__ bo, float* __restrict__ out) {
  const int m0 = blockIdx.x * 128, n0 = blockIdx.y * 128;
  __shared__ __align__(16) _Float16 Alds[128][32];
  __shared__ __align__(16) _Float16 Blds[128][32];
  const int tid = threadIdx.x;
  const int l = tid & 63, w = tid >> 6;
  const int wm = w >> 1, wn = w & 1;
  const int lr = l & 15, lg = l >> 4;
  f32x4 acc[4][4] = {};
  for (int kt = 0; kt < 32; ++kt) {
    const int k0 = kt * 32;
#pragma unroll
    for (int i = 0; i < 2; ++i) {
      int g = tid + i * 256;
      int r = g >> 2, c8 = (g & 3) * 8;
      *(half8*)&Alds[r][c8] = *(const half8*)(attC + (size_t)(m0 + r) * Dc + k0 + c8);
      *(half8*)&Blds[r][c8] = *(const half8*)(WoT + (size_t)(n0 + r) * Dc + k0 + c8);
    }
    __syncthreads();
    half8 af[4], bf[4];
#pragma unroll
    for (int i2 = 0; i2 < 4; ++i2) {
      af[i2] = *(const half8*)&Alds[wm * 64 + i2 * 16 + lr][lg * 8];
      bf[i2] = *(const half8*)&Blds[wn * 64 + i2 * 16 + lr][lg * 8];
    }
#pragma unroll
    for (int am = 0; am < 4; ++am)
#pragma unroll
      for (int bn = 0; bn < 4; ++bn)
        acc[am][bn] = __builtin_amdgcn_mfma_f32_16x16x32_f16(af[am], bf[bn], acc[am][bn], 0, 0, 0);
    __syncthreads();
  }
#pragma unroll
  for (int am = 0; am < 4; ++am)
#pragma unroll
    for (int bn = 0; bn < 4; ++bn) {
      int n = n0 + wn * 64 + bn * 16 + lr;
      float bias = bo[n];
#pragma unroll
      for (int r = 0; r < 4; ++r) {
        int m = m0 + wm * 64 + am * 16 + lg * 4 + r;
        out[(size_t)m * Dc + n] = acc[am][bn][r] + bias;
      }
    }
}

// ---------------------------------------------------------------------------
extern "C" void kernel_launch(void* const* d_in, const int* in_sizes, int n_in,
                              void* d_out, int out_size, void* d_ws, size_t ws_size,
                              hipStream_t stream) {
  const float* x  = (const float*)d_in[0];
  const float* Wq = (const float*)d_in[1];
  const float* Wk = (const float*)d_in[2];
  const float* Wv = (const float*)d_in[3];
  const float* Wo = (const float*)d_in[4];
  const float* bo = (const float*)d_in[5];
  float* out = (float*)d_out;
  char* ws = (char*)d_ws;
  _Float16* Qp   = (_Float16*)(ws);                        // [0,8M)
  _Float16* Kp   = (_Float16*)(ws + (size_t)(8  << 20));   // [8M,16M)
  _Float16* Vp   = (_Float16*)(ws + (size_t)(16 << 20));   // [16M,24M)
  _Float16* WoT  = (_Float16*)(ws + (size_t)(24 << 20));   // [24M,26M)
  _Float16* WT   = (_Float16*)(ws + (size_t)(26 << 20));   // [26M,26.4M) dead after qkv
  _Float16* attC = (_Float16*)(ws + (size_t)(26 << 20));   // [26M,34M) written in flash

  prep_w<<<dim3(48), dim3(256), 0, stream>>>(Wq, Wk, Wv, WT);
  prep_wo<<<dim3(16, 16), dim3(256), 0, stream>>>(Wo, WoT);
  qkv_proj<<<dim3(512), dim3(256), 0, stream>>>(x, WT, Qp, Kp, Vp);
  flash_attn<<<dim3(2048), dim3(64), 0, stream>>>(Qp, Kp, Vp, attC);
  out_proj<<<dim3(32, 8), dim3(256), 0, stream>>>(attC, WoT, bo, out);
}

// Round 6
// 88.720 us; speedup vs baseline: 2.5165x; 1.1316x over previous
//
#include <hip/hip_runtime.h>

typedef __attribute__((ext_vector_type(8))) _Float16 half8;
typedef __attribute__((ext_vector_type(2))) __fp16 fp16x2;
typedef __attribute__((ext_vector_type(4))) float f32x4;
typedef __attribute__((ext_vector_type(16))) float f32x16;

constexpr int Bc = 2, Sc = 2048, Dc = 1024, Hc = 16, HDc = 64;

// LDS swizzle for [rows][64] f16 tiles (qkv_proj x-tile only).
__device__ __forceinline__ int swz(int row, int colh) {
  return row * 64 + (colh ^ ((row & 7) * 8));
}

#define PKU(a, b) __builtin_bit_cast(unsigned, __builtin_amdgcn_cvt_pkrtz((a), (b)))

// pack 2 groups-of-4 f32 (my half of two adjacent 8-elem groups), exchange
// halves across the hi=lane>>5 split, store one fragment half8.
#define PACK_STORE(vA0, vA1, vA2, vA3, vB0, vB1, vB2, vB3, ptr) {        \
  unsigned W0 = PKU(vA0, vA1), W1 = PKU(vA2, vA3);                       \
  unsigned X0 = PKU(vB0, vB1), X1 = PKU(vB2, vB3);                       \
  unsigned s0_ = (unsigned)__shfl_xor((int)(hi ? W0 : X0), 32);          \
  unsigned s1_ = (unsigned)__shfl_xor((int)(hi ? W1 : X1), 32);          \
  union { unsigned u[4]; half8 h8; } P_;                                 \
  P_.u[0] = hi ? s0_ : W0; P_.u[1] = hi ? s1_ : W1;                      \
  P_.u[2] = hi ? X0 : s0_; P_.u[3] = hi ? X1 : s1_;                      \
  *(half8*)(ptr) = P_.h8; }

// ---------------------------------------------------------------------------
// prep_w: WT[m][h][e][d] = (f16) W_m[h][d][e]  (transpose per head, cast f16).
// Wq additionally scaled by 0.125*log2(e) (folds softmax scale + exp2 domain).
__global__ __launch_bounds__(256) void prep_w(const float* __restrict__ Wq,
                                              const float* __restrict__ Wk,
                                              const float* __restrict__ Wv,
                                              _Float16* __restrict__ WT) {
  const int m = blockIdx.x >> 4;
  const int h = blockIdx.x & 15;
  const float* src = (m == 0 ? Wq : (m == 1 ? Wk : Wv)) + (size_t)h * 4096;
  const float scale = (m == 0) ? 0.125f * 1.44269504088896f : 1.0f;
  __shared__ float T[64][65];
  const int tid = threadIdx.x;
#pragma unroll
  for (int i = 0; i < 4; ++i) {
    int r = (tid >> 4) + 16 * i, c4 = (tid & 15) * 4;
    *(float4*)&T[r][c4] = *(const float4*)(src + r * 64 + c4);
  }
  __syncthreads();
  _Float16* dst = WT + ((size_t)m * 16 + h) * 4096;
#pragma unroll
  for (int i = 0; i < 4; ++i) {
    int e = (tid >> 4) + 16 * i, d4 = (tid & 15) * 4;
    union { _Float16 hh[4]; unsigned long long u; } pk;
#pragma unroll
    for (int j = 0; j < 4; ++j) pk.hh[j] = (_Float16)(T[d4 + j][e] * scale);
    *(unsigned long long*)(dst + (size_t)e * 64 + d4) = pk.u;
  }
}

// ---------------------------------------------------------------------------
// prep_wo: WoT[n][k'] = (f16) Wo[orig(k')][n], k' = h*64+e, orig = e*16+h.
__global__ __launch_bounds__(256) void prep_wo(const float* __restrict__ Wo,
                                               _Float16* __restrict__ WoT) {
  __shared__ float T[64][68];
  const int hh = blockIdx.x;
  const int n0 = blockIdx.y * 64;
  const int tid = threadIdx.x;
#pragma unroll
  for (int i = 0; i < 4; ++i) {
    int g = tid + i * 256;
    int e = g >> 4, c4 = (g & 15) * 4;
    *(float4*)&T[e][c4] = *(const float4*)(Wo + (size_t)(e * 16 + hh) * Dc + n0 + c4);
  }
  __syncthreads();
#pragma unroll
  for (int i = 0; i < 4; ++i) {
    int g = tid + i * 256;
    int c = g >> 4, e4 = (g & 15) * 4;
    union { _Float16 h[4]; unsigned long long u; } pk;
    pk.h[0] = (_Float16)T[e4 + 0][c];
    pk.h[1] = (_Float16)T[e4 + 1][c];
    pk.h[2] = (_Float16)T[e4 + 2][c];
    pk.h[3] = (_Float16)T[e4 + 3][c];
    *(unsigned long long*)(WoT + (size_t)(n0 + c) * Dc + hh * 64 + e4) = pk.u;
  }
}

// ---------------------------------------------------------------------------
// qkv_proj (MFMA): block = (b, 128-row s-tile, h). 4 waves x 32 s-rows.
// Q^T,K^T via mfma(W^T, x) (lane holds e-rows for its s-col); V via mfma(x, W^T)
// (lane holds s-rows for its e-col). cvt_pkrtz + shfl_xor(32) assembles exact
// MFMA fragment half8s -> 12 coalesced 16B stores/thread, zero scatter.
// Fragment layouts (chunk = 512 halves, addr = chunk*512 + lane*8 + elem):
//  Q'[(bh*64+qt)*4 + (e>>4)]                lane=((e>>3)&1)*32+(s&31), elem=e&7
//  K'[(bh*32+kt)*8 + ((s>>5)&1)*4 + (e>>4)] lane=((e>>3)&1)*32+(s&31), elem=e&7
//  V'[(bh*32+kt)*8 + (e>>5)*4 + ((s>>4)&3)] lane=((s>>3)&1)*32+(e&31), elem=s&7
__global__ __launch_bounds__(256) void qkv_proj(
    const float* __restrict__ x, const _Float16* __restrict__ WT,
    _Float16* __restrict__ Qp, _Float16* __restrict__ Kp,
    _Float16* __restrict__ Vp) {
  const int h = blockIdx.x & 15;
  const int st = (blockIdx.x >> 4) & 15;
  const int b = blockIdx.x >> 8;
  const int s0 = st * 128;
  __shared__ __align__(16) _Float16 xs[128 * 64];
  const int tid = threadIdx.x;
#pragma unroll
  for (int i = 0; i < 4; ++i) {
    int r = (tid >> 3) + 32 * i;
    int c8 = (tid & 7) * 8;
    const float* xp = x + ((size_t)(b * Sc + s0 + r)) * Dc + h * 64 + c8;
    float4 u0 = *(const float4*)xp;
    float4 u1 = *(const float4*)(xp + 4);
    union { fp16x2 h2[4]; half8 h8; } pk;
    pk.h2[0] = __builtin_amdgcn_cvt_pkrtz(u0.x, u0.y);
    pk.h2[1] = __builtin_amdgcn_cvt_pkrtz(u0.z, u0.w);
    pk.h2[2] = __builtin_amdgcn_cvt_pkrtz(u1.x, u1.y);
    pk.h2[3] = __builtin_amdgcn_cvt_pkrtz(u1.z, u1.w);
    *(half8*)&xs[swz(r, c8)] = pk.h8;
  }
  __syncthreads();
  const int l = tid & 63, w = tid >> 6;
  const int lq = l & 31, hi = l >> 5;
  half8 xa[4];
#pragma unroll
  for (int c = 0; c < 4; ++c)
    xa[c] = *(const half8*)&xs[swz(32 * w + lq, c * 16 + hi * 8)];

  const _Float16* WTq = WT + (size_t)h * 4096;
  const _Float16* WTk = WT + (size_t)(16 + h) * 4096;
  const _Float16* WTv = WT + (size_t)(32 + h) * 4096;
  f32x16 Qt[2] = {}, Kt[2] = {}, Vd[2] = {};
#pragma unroll
  for (int et = 0; et < 2; ++et) {
#pragma unroll
    for (int c = 0; c < 4; ++c) {
      const int off = (32 * et + lq) * 64 + c * 16 + hi * 8;
      half8 wqf = *(const half8*)(WTq + off);
      half8 wkf = *(const half8*)(WTk + off);
      half8 wvf = *(const half8*)(WTv + off);
      Qt[et] = __builtin_amdgcn_mfma_f32_32x32x16_f16(wqf, xa[c], Qt[et], 0, 0, 0);
      Kt[et] = __builtin_amdgcn_mfma_f32_32x32x16_f16(wkf, xa[c], Kt[et], 0, 0, 0);
      Vd[et] = __builtin_amdgcn_mfma_f32_32x32x16_f16(xa[c], wvf, Vd[et], 0, 0, 0);
    }
  }
  const int bh = b * Hc + h;
  const int qt_ = 4 * st + w;
  const int ktile = 2 * st + (w >> 1);
  _Float16* qdst = Qp + (((size_t)(bh * 64 + qt_) * 4) << 9) + (l << 3);
  _Float16* kdst = Kp + (((size_t)((bh * 32 + ktile) * 8) + (w & 1) * 4) << 9) + (l << 3);
  _Float16* vdst = Vp + (((size_t)(bh * 32 + ktile) * 8) << 9) + (l << 3);

  PACK_STORE(Qt[0][0], Qt[0][1], Qt[0][2], Qt[0][3], Qt[0][4], Qt[0][5], Qt[0][6], Qt[0][7], qdst + (0 << 9));
  PACK_STORE(Qt[0][8], Qt[0][9], Qt[0][10], Qt[0][11], Qt[0][12], Qt[0][13], Qt[0][14], Qt[0][15], qdst + (1 << 9));
  PACK_STORE(Qt[1][0], Qt[1][1], Qt[1][2], Qt[1][3], Qt[1][4], Qt[1][5], Qt[1][6], Qt[1][7], qdst + (2 << 9));
  PACK_STORE(Qt[1][8], Qt[1][9], Qt[1][10], Qt[1][11], Qt[1][12], Qt[1][13], Qt[1][14], Qt[1][15], qdst + (3 << 9));

  PACK_STORE(Kt[0][0], Kt[0][1], Kt[0][2], Kt[0][3], Kt[0][4], Kt[0][5], Kt[0][6], Kt[0][7], kdst + (0 << 9));
  PACK_STORE(Kt[0][8], Kt[0][9], Kt[0][10], Kt[0][11], Kt[0][12], Kt[0][13], Kt[0][14], Kt[0][15], kdst + (1 << 9));
  PACK_STORE(Kt[1][0], Kt[1][1], Kt[1][2], Kt[1][3], Kt[1][4], Kt[1][5], Kt[1][6], Kt[1][7], kdst + (2 << 9));
  PACK_STORE(Kt[1][8], Kt[1][9], Kt[1][10], Kt[1][11], Kt[1][12], Kt[1][13], Kt[1][14], Kt[1][15], kdst + (3 << 9));

#pragma unroll
  for (int et = 0; et < 2; ++et) {
    PACK_STORE(Vd[et][0], Vd[et][1], Vd[et][2], Vd[et][3], Vd[et][4], Vd[et][5], Vd[et][6], Vd[et][7],
               vdst + ((size_t)(et * 4 + ((2 * w + 0) & 3)) << 9));
    PACK_STORE(Vd[et][8], Vd[et][9], Vd[et][10], Vd[et][11], Vd[et][12], Vd[et][13], Vd[et][14], Vd[et][15],
               vdst + ((size_t)(et * 4 + ((2 * w + 1) & 3)) << 9));
  }
}

// ---------------------------------------------------------------------------
// flash_attn v4: 1 wave/block, 32 q-rows, no LDS/barriers. Register
// double-buffered K prefetch (unroll-by-2, named even/odd buffers) hides the
// per-tile L2 latency under the previous tile's softmax+PV.
__global__ __launch_bounds__(64, 2) void flash_attn(
    const _Float16* __restrict__ Qp, const _Float16* __restrict__ Kp,
    const _Float16* __restrict__ Vp, _Float16* __restrict__ attC) {
  const int i = blockIdx.x;
  const int xcd = i & 7, j = i >> 3;
  const int bh = xcd * 4 + (j & 3);
  const int qt = 63 - (j >> 2);   // longest tiles first (LPT)
  const int q0 = qt * 32;
  const int NT = qt / 2 + 1;
  const int b = bh >> 4, h = bh & 15;
  const int l = threadIdx.x, lq = l & 31, hi = l >> 5;
  const int q_global = q0 + lq;
  const size_t kvb = (size_t)bh * 32;

  const _Float16* qb = Qp + (((size_t)(bh * 64 + qt) * 4) << 9) + (l << 3);
  half8 qf[4];
#pragma unroll
  for (int c = 0; c < 4; ++c) qf[c] = *(const half8*)(qb + (c << 9));

  f32x16 OA = {}, OB = {};
  float m_run = -1e30f, l_run = 0.f;
  half8 kaE[4], kbE[4], kaO[4], kbO[4];

#define DOB(t) (((t) * 64 + 32) <= q0 + 31)

#define LOADK(KA, KB, t) {                                                    \
  const _Float16* p8 = Kp + (((kvb + (t)) * 8) << 9) + (l << 3);              \
  _Pragma("unroll") for (int c = 0; c < 4; ++c)                               \
    KA[c] = *(const half8*)(p8 + (c << 9));                                   \
  if (DOB(t)) {                                                               \
    _Pragma("unroll") for (int c = 0; c < 4; ++c)                             \
      KB[c] = *(const half8*)(p8 + ((4 + c) << 9));                           \
  } }

#define STEP(KA, KB, t) {                                                     \
  const int k0 = (t) * 64;                                                    \
  const bool doB = DOB(t);                                                    \
  const _Float16* vp8 = Vp + (((kvb + (t)) * 8) << 9) + (l << 3);             \
  half8 va[4], vb[4];                                                         \
  _Pragma("unroll") for (int c = 0; c < 4; ++c) {                             \
    va[c] = *(const half8*)(vp8 + (c << 9));                                  \
    vb[c] = *(const half8*)(vp8 + ((4 + c) << 9));                            \
  }                                                                           \
  f32x16 SA = {}, SB = {};                                                    \
  __builtin_amdgcn_s_setprio(1);                                              \
  _Pragma("unroll") for (int c = 0; c < 4; ++c)                               \
    SA = __builtin_amdgcn_mfma_f32_32x32x16_f16(KA[c], qf[c], SA, 0, 0, 0);   \
  if (doB) {                                                                  \
    _Pragma("unroll") for (int c = 0; c < 4; ++c)                             \
      SB = __builtin_amdgcn_mfma_f32_32x32x16_f16(KB[c], qf[c], SB, 0, 0, 0); \
  }                                                                           \
  __builtin_amdgcn_s_setprio(0);                                              \
  if (k0 + 63 > q0) {                                                         \
    _Pragma("unroll") for (int r = 0; r < 16; ++r) {                          \
      const int kk = k0 + (r & 3) + 8 * (r >> 2) + 4 * hi;                    \
      if (kk > q_global) SA[r] = -1e30f;                                      \
      if (doB && kk + 32 > q_global) SB[r] = -1e30f;                          \
    }                                                                         \
  }                                                                           \
  float mx = -1e30f;                                                          \
  _Pragma("unroll") for (int r = 0; r < 16; ++r) mx = fmaxf(mx, SA[r]);       \
  if (doB) {                                                                  \
    _Pragma("unroll") for (int r = 0; r < 16; ++r) mx = fmaxf(mx, SB[r]);     \
  }                                                                           \
  mx = fmaxf(mx, __shfl_xor(mx, 32));                                         \
  if (!__all(mx <= m_run + 4.0f)) {                                           \
    const float mnew = fmaxf(m_run, mx);                                      \
    const float corr = __builtin_amdgcn_exp2f(m_run - mnew);                  \
    l_run *= corr;                                                            \
    _Pragma("unroll") for (int r = 0; r < 16; ++r) { OA[r] *= corr; OB[r] *= corr; } \
    m_run = mnew;                                                             \
  }                                                                           \
  float Pv[32];                                                               \
  float ls = 0.f;                                                             \
  _Pragma("unroll") for (int r = 0; r < 16; ++r) {                            \
    Pv[r] = __builtin_amdgcn_exp2f(SA[r] - m_run);                            \
    ls += Pv[r];                                                              \
  }                                                                           \
  if (doB) {                                                                  \
    _Pragma("unroll") for (int r = 0; r < 16; ++r) {                          \
      Pv[16 + r] = __builtin_amdgcn_exp2f(SB[r] - m_run);                     \
      ls += Pv[16 + r];                                                       \
    }                                                                         \
  }                                                                           \
  ls += __shfl_xor(ls, 32);                                                   \
  l_run += ls;                                                                \
  __builtin_amdgcn_s_setprio(1);                                              \
  _Pragma("unroll") for (int ch = 0; ch < 4; ++ch) {                          \
    if (ch < (doB ? 4 : 2)) {                                                 \
      unsigned W0 = PKU(Pv[ch * 8 + 0], Pv[ch * 8 + 1]);                      \
      unsigned W1 = PKU(Pv[ch * 8 + 2], Pv[ch * 8 + 3]);                      \
      unsigned W2 = PKU(Pv[ch * 8 + 4], Pv[ch * 8 + 5]);                      \
      unsigned W3 = PKU(Pv[ch * 8 + 6], Pv[ch * 8 + 7]);                      \
      unsigned sw0 = (unsigned)__shfl_xor((int)(hi ? W0 : W2), 32);           \
      unsigned sw1 = (unsigned)__shfl_xor((int)(hi ? W1 : W3), 32);           \
      union { unsigned u[4]; half8 h; } pa;                                   \
      pa.u[0] = hi ? sw0 : W0;                                                \
      pa.u[1] = hi ? sw1 : W1;                                                \
      pa.u[2] = hi ? W2 : sw0;                                                \
      pa.u[3] = hi ? W3 : sw1;                                                \
      OA = __builtin_amdgcn_mfma_f32_32x32x16_f16(va[ch], pa.h, OA, 0, 0, 0); \
      OB = __builtin_amdgcn_mfma_f32_32x32x16_f16(vb[ch], pa.h, OB, 0, 0, 0); \
    }                                                                         \
  }                                                                           \
  __builtin_amdgcn_s_setprio(0); }

  LOADK(kaE, kbE, 0);
  int kt = 0;
  for (; kt + 2 <= NT; kt += 2) {
    LOADK(kaO, kbO, kt + 1);
    STEP(kaE, kbE, kt);
    if (kt + 2 < NT) { LOADK(kaE, kbE, kt + 2); }
    STEP(kaO, kbO, kt + 1);
  }
  if (kt < NT) { STEP(kaE, kbE, kt); }

  // OA[r] = O^T[e = (r&3)+8*(r>>2)+4*hi][q_global]; OB -> e+32.
  const float inv = 1.f / l_run;
  _Float16* op = attC + ((size_t)b * Sc + q_global) * Dc + h * 64;
#pragma unroll
  for (int g = 0; g < 4; ++g) {
    union { _Float16 hh[4]; unsigned long long u; } pA, pB;
#pragma unroll
    for (int jj = 0; jj < 4; ++jj) {
      pA.hh[jj] = (_Float16)(OA[4 * g + jj] * inv);
      pB.hh[jj] = (_Float16)(OB[4 * g + jj] * inv);
    }
    *(unsigned long long*)(op + 8 * g + 4 * hi) = pA.u;
    *(unsigned long long*)(op + 32 + 8 * g + 4 * hi) = pB.u;
  }
}

// ---------------------------------------------------------------------------
// out_proj: C[4096][1024] = attC @ WoT^T + bo. 128x128 tile, BK=32, 4 waves.
__global__ __launch_bounds__(256) void out_proj(
    const _Float16* __restrict__ attC, const _Float16* __restrict__ WoT,
    const float* __restrict__ bo, float* __restrict__ out) {
  const int m0 = blockIdx.x * 128, n0 = blockIdx.y * 128;
  __shared__ __align__(16) _Float16 Alds[128][32];
  __shared__ __align__(16) _Float16 Blds[128][32];
  const int tid = threadIdx.x;
  const int l = tid & 63, w = tid >> 6;
  const int wm = w >> 1, wn = w & 1;
  const int lr = l & 15, lg = l >> 4;
  f32x4 acc[4][4] = {};
  for (int kt = 0; kt < 32; ++kt) {
    const int k0 = kt * 32;
#pragma unroll
    for (int i = 0; i < 2; ++i) {
      int g = tid + i * 256;
      int r = g >> 2, c8 = (g & 3) * 8;
      *(half8*)&Alds[r][c8] = *(const half8*)(attC + (size_t)(m0 + r) * Dc + k0 + c8);
      *(half8*)&Blds[r][c8] = *(const half8*)(WoT + (size_t)(n0 + r) * Dc + k0 + c8);
    }
    __syncthreads();
    half8 af[4], bf[4];
#pragma unroll
    for (int i2 = 0; i2 < 4; ++i2) {
      af[i2] = *(const half8*)&Alds[wm * 64 + i2 * 16 + lr][lg * 8];
      bf[i2] = *(const half8*)&Blds[wn * 64 + i2 * 16 + lr][lg * 8];
    }
#pragma unroll
    for (int am = 0; am < 4; ++am)
#pragma unroll
      for (int bn = 0; bn < 4; ++bn)
        acc[am][bn] = __builtin_amdgcn_mfma_f32_16x16x32_f16(af[am], bf[bn], acc[am][bn], 0, 0, 0);
    __syncthreads();
  }
#pragma unroll
  for (int am = 0; am < 4; ++am)
#pragma unroll
    for (int bn = 0; bn < 4; ++bn) {
      int n = n0 + wn * 64 + bn * 16 + lr;
      float bias = bo[n];
#pragma unroll
      for (int r = 0; r < 4; ++r) {
        int m = m0 + wm * 64 + am * 16 + lg * 4 + r;
        out[(size_t)m * Dc + n] = acc[am][bn][r] + bias;
      }
    }
}

// ---------------------------------------------------------------------------
extern "C" void kernel_launch(void* const* d_in, const int* in_sizes, int n_in,
                              void* d_out, int out_size, void* d_ws, size_t ws_size,
                              hipStream_t stream) {
  const float* x  = (const float*)d_in[0];
  const float* Wq = (const float*)d_in[1];
  const float* Wk = (const float*)d_in[2];
  const float* Wv = (const float*)d_in[3];
  const float* Wo = (const float*)d_in[4];
  const float* bo = (const float*)d_in[5];
  float* out = (float*)d_out;
  char* ws = (char*)d_ws;
  _Float16* Qp   = (_Float16*)(ws);                        // [0,8M)
  _Float16* Kp   = (_Float16*)(ws + (size_t)(8  << 20));   // [8M,16M)
  _Float16* Vp   = (_Float16*)(ws + (size_t)(16 << 20));   // [16M,24M)
  _Float16* WoT  = (_Float16*)(ws + (size_t)(24 << 20));   // [24M,26M)
  _Float16* WT   = (_Float16*)(ws + (size_t)(26 << 20));   // [26M,26.4M) dead after qkv
  _Float16* attC = (_Float16*)(ws + (size_t)(26 << 20));   // [26M,34M) written in flash

  prep_w<<<dim3(48), dim3(256), 0, stream>>>(Wq, Wk, Wv, WT);
  prep_wo<<<dim3(16, 16), dim3(256), 0, stream>>>(Wo, WoT);
  qkv_proj<<<dim3(512), dim3(256), 0, stream>>>(x, WT, Qp, Kp, Vp);
  flash_attn<<<dim3(2048), dim3(64), 0, stream>>>(Qp, Kp, Vp, attC);
  out_proj<<<dim3(32, 8), dim3(256), 0, stream>>>(attC, WoT, bo, out);
}